// Round 14
// 474.111 us; speedup vs baseline: 1.1322x; 1.0273x over previous
//
#include <hip/hip_runtime.h>
#include <hip/hip_bf16.h>
#include <hip/hip_fp8.h>

typedef __hip_bfloat16 hb;
typedef __bf16 bf16x8 __attribute__((ext_vector_type(8)));
typedef __bf16 bf16x4 __attribute__((ext_vector_type(4)));
typedef float f32x4 __attribute__((ext_vector_type(4)));

#define SEQ 4096
#define EMBED 1024
#define NHEAD 4
#define HDIM 256
#define FFD 4096
#define NEXP 8
#define ADIM 496
#define NSLOT 9216  // 8192 assignments + 8 experts x 127 max padding, 128-aligned

static __device__ __forceinline__ float b2f(hb x) { return __bfloat162float(x); }
static __device__ __forceinline__ hb f2b(float x) { return __float2bfloat16(x); }
static __device__ __forceinline__ unsigned char f2e4m3(float v) {
  __hip_fp8_e4m3 t(v);
  return t.__x;
}
// Fast f32 -> e4m3fn for x in [2^-6, 448] (positive normals only): RNE at the
// 3-bit mantissa cut, then rebias 127->7. Caller must clamp into range.
static __device__ __forceinline__ unsigned char f2e4m3_fast(float x) {
  unsigned u = __float_as_uint(x);
  u += 0x7FFFFu + ((u >> 20) & 1u);
  return (unsigned char)((u >> 20) - 960u);
}

// gfx950 hardware fp8 conversion (v_cvt_pk_fp8_f32: 2 f32 -> 2 e4m3 bytes,
// RNE, saturating, subnormal-correct). Same HW feature as the fp8 MFMAs
// already used here. Fallback keeps the round-13 software paths.
#if defined(__has_builtin)
#if __has_builtin(__builtin_amdgcn_cvt_pk_fp8_f32)
#define HW_FP8 1
#endif
#endif
#ifndef HW_FP8
#define HW_FP8 0
#endif

static __device__ __forceinline__ unsigned cvt2_fp8(float a, float b) {
#if HW_FP8
  return (unsigned)__builtin_amdgcn_cvt_pk_fp8_f32(a, b, 0, false) & 0xffffu;
#else
  return (unsigned)f2e4m3(a) | ((unsigned)f2e4m3(b) << 8);
#endif
}
// positive-only variant (exp outputs; fallback clamps into fast-path range)
static __device__ __forceinline__ unsigned cvt2_fp8_pos(float a, float b) {
#if HW_FP8
  return (unsigned)__builtin_amdgcn_cvt_pk_fp8_f32(a, b, 0, false) & 0xffffu;
#else
  const float ca = fminf(fmaxf(a, 0.015625f), 448.f);
  const float cb = fminf(fmaxf(b, 0.015625f), 448.f);
  return (unsigned)f2e4m3_fast(ca) | ((unsigned)f2e4m3_fast(cb) << 8);
#endif
}

#define GLOAD_LDS16(g, l)                                                      \
  __builtin_amdgcn_global_load_lds(                                            \
      (const __attribute__((address_space(1))) void*)(g),                      \
      (__attribute__((address_space(3))) void*)(l), 16, 0, 0)

// ---------------------------------------------------------------------------
// Shared GEMM K-loop, BK=64 (2 panels of 32): halves barrier count vs BK=32,
// doubles MFMA per barrier. LDS: 2 x 128x64 bf16 = 32 KB. Panel-local XOR
// swizzle keeps fragment reads at the free 2-way conflict level (m136).
// ---------------------------------------------------------------------------
#define GEMM_KLOOP64(KMAX)                                                     \
  for (int kt = 0; kt < (KMAX); kt += 64) {                                    \
    GLOAD_LDS16(Ag + kt, sA + wave * 512);                                     \
    GLOAD_LDS16(Ag + kt + 32, sA + 4096 + wave * 512);                         \
    GLOAD_LDS16(Ag + kt + 64 * lda_, sA + 2048 + wave * 512);                  \
    GLOAD_LDS16(Ag + kt + 64 * lda_ + 32, sA + 6144 + wave * 512);             \
    GLOAD_LDS16(Bg + kt, sB + wave * 512);                                     \
    GLOAD_LDS16(Bg + kt + 32, sB + 4096 + wave * 512);                         \
    GLOAD_LDS16(Bg + kt + 64 * ldb_, sB + 2048 + wave * 512);                  \
    GLOAD_LDS16(Bg + kt + 64 * ldb_ + 32, sB + 6144 + wave * 512);             \
    __syncthreads();                                                           \
    _Pragma("unroll") for (int ks = 0; ks < 2; ks++) {                         \
      bf16x8 av[4], bv[4];                                                     \
      _Pragma("unroll") for (int i = 0; i < 4; i++) {                          \
        const int row = wr * 64 + i * 16 + lm;                                 \
        av[i] = *(const bf16x8*)&sA[ks * 4096 + row * 32 + sw8];               \
      }                                                                        \
      _Pragma("unroll") for (int i = 0; i < 4; i++) {                          \
        const int row = wc * 64 + i * 16 + lm;                                 \
        bv[i] = *(const bf16x8*)&sB[ks * 4096 + row * 32 + sw8];               \
      }                                                                        \
      _Pragma("unroll") for (int i = 0; i < 4; i++)                            \
          _Pragma("unroll") for (int j = 0; j < 4; j++) acc[i][j] =            \
          __builtin_amdgcn_mfma_f32_16x16x32_bf16(av[i], bv[j], acc[i][j], 0,  \
                                                  0, 0);                       \
    }                                                                          \
    __syncthreads();                                                           \
  }

// XCD-aware chunked block swizzle (T1): consecutive launch-order blocks land
// on the same XCD as a contiguous tile chunk -> A-panels become L2-resident.
// Bijective because every grid here has (gridDim.x*gridDim.y) % 8 == 0
// (1024/768/576/256/128/64 - audited). Tile-order permutation only.
#define XCD_SWZ128                                                             \
  const int nwg_ = gridDim.x * gridDim.y;                                      \
  const int lin_ = blockIdx.y * gridDim.x + blockIdx.x;                        \
  const int swz_ = (lin_ & 7) * (nwg_ >> 3) + (lin_ >> 3);                     \
  const int bx_ = swz_ % gridDim.x, by_ = swz_ / gridDim.x;                    \
  const int m0 = by_ * 128, n0 = bx_ * 128;

#define GEMM_PROLOGUE                                                          \
  XCD_SWZ128                                                                   \
  const int tid = threadIdx.x;                                                 \
  const int wave = tid >> 6, lane = tid & 63;                                  \
  const int quad = lane >> 4, lm = lane & 15;                                  \
  const int wr = wave >> 1, wc = wave & 1;                                     \
  const int r0 = tid >> 2;                                                     \
  const int cg = 8 * ((tid & 3) ^ ((tid >> 2) & 3));                           \
  const int sw8 = (quad ^ (lm & 3)) * 8;

// bf16 coalesced epilogue via wave-private LDS stage (full 128B lines)
#define EPILOGUE_B16(DST, LDC)                                                 \
  {                                                                            \
    hb* eb = smem + wave * 1024;                                               \
    _Pragma("unroll") for (int i = 0; i < 4; i++) {                            \
      _Pragma("unroll") for (int j = 0; j < 4; j++) {                          \
        const int c = ((j ^ quad) << 4) + lm;                                  \
        _Pragma("unroll") for (int rr = 0; rr < 4; rr++)                       \
            eb[(quad * 4 + rr) * 64 + c] = f2b(acc[i][j][rr]);                 \
      }                                                                        \
      _Pragma("unroll") for (int p = 0; p < 2; p++) {                          \
        const int r = p * 8 + (lane >> 3);                                     \
        const int cgc = lane & 7;                                              \
        const int gs = (cgc >> 1) ^ (r >> 2);                                  \
        const bf16x8 val =                                                     \
            *(const bf16x8*)&eb[r * 64 + gs * 16 + (cgc & 1) * 8];             \
        const long grow = m0 + wr * 64 + i * 16 + r;                           \
        *(bf16x8*)&DST[grow * (LDC) + n0 + wc * 64 + cgc * 8] = val;           \
      }                                                                        \
    }                                                                          \
  }

// ---------------------------------------------------------------------------
// Generic batched GEMM: C[M,N] = A[M,K] @ Bt[N,K]^T (+bias[col]) (+relu)
// ---------------------------------------------------------------------------
__global__ __launch_bounds__(256) void gemm_bt(
    const hb* __restrict__ A, long lda, long bA,
    const hb* __restrict__ B, long ldb, long bB,
    hb* __restrict__ C, long ldc, long bC,
    int K, const float* __restrict__ bias, int relu) {
  __shared__ __align__(16) hb smem[2 * 128 * 64];
  hb* sA = smem;
  hb* sB = smem + 8192;
  const int z = blockIdx.z;
  A += (long)z * bA;
  B += (long)z * bB;
  C += (long)z * bC;
  GEMM_PROLOGUE
  const long lda_ = lda, ldb_ = ldb;
  const hb* Ag = A + (long)(m0 + r0) * lda + cg;
  const hb* Bg = B + (long)(n0 + r0) * ldb + cg;

  f32x4 acc[4][4] = {};
  GEMM_KLOOP64(K)

  hb* eb = smem + wave * 1024;
#pragma unroll
  for (int i = 0; i < 4; i++) {
#pragma unroll
    for (int j = 0; j < 4; j++) {
      const float bval = bias ? bias[n0 + wc * 64 + j * 16 + lm] : 0.f;
      const int c = ((j ^ quad) << 4) + lm;  // swizzled col
#pragma unroll
      for (int rr = 0; rr < 4; rr++) {
        float v = acc[i][j][rr] + bval;
        if (relu) v = fmaxf(v, 0.f);
        eb[(quad * 4 + rr) * 64 + c] = f2b(v);
      }
    }
#pragma unroll
    for (int p = 0; p < 2; p++) {
      const int r = p * 8 + (lane >> 3);
      const int cgc = lane & 7;
      const int gs = (cgc >> 1) ^ (r >> 2);
      const bf16x8 val = *(const bf16x8*)&eb[r * 64 + gs * 16 + (cgc & 1) * 8];
      const long grow = m0 + wr * 64 + i * 16 + r;
      *(bf16x8*)&C[grow * ldc + n0 + wc * 64 + cgc * 8] = val;
    }
  }
}

// ---------------------------------------------------------------------------
// qkv GEMM (big path): C = moe @ inprojT^T + bias. Output cols < 2048 (Q,K)
// are written ONLY as fp8 e4m3 to qk8[4096][2048] (HW cvt_pk when available:
// handles negatives + subnormals natively). Cols >= 2048 (V) bf16 to C.
// ---------------------------------------------------------------------------
__global__ __launch_bounds__(256) void gemm_bt_qkv(
    const hb* __restrict__ A, const hb* __restrict__ B,
    hb* __restrict__ C, const float* __restrict__ bias,
    unsigned char* __restrict__ qk8) {
  __shared__ __align__(16) hb smem[2 * 128 * 64];
  hb* sA = smem;
  hb* sB = smem + 8192;
  GEMM_PROLOGUE
  const long lda_ = 1024, ldb_ = 1024;
  const hb* Ag = A + (long)(m0 + r0) * 1024 + cg;
  const hb* Bg = B + (long)(n0 + r0) * 1024 + cg;

  f32x4 acc[4][4] = {};
  GEMM_KLOOP64(1024)

  hb* eb = smem + wave * 1024;
  const bool doq = (n0 < 2048);
#pragma unroll
  for (int i = 0; i < 4; i++) {
#pragma unroll
    for (int j = 0; j < 4; j++) {
      const float bval = bias[n0 + wc * 64 + j * 16 + lm];
      const int c = ((j ^ quad) << 4) + lm;
#pragma unroll
      for (int rr = 0; rr < 4; rr++)
        eb[(quad * 4 + rr) * 64 + c] = f2b(acc[i][j][rr] + bval);
    }
#pragma unroll
    for (int p = 0; p < 2; p++) {
      const int r = p * 8 + (lane >> 3);
      const int cgc = lane & 7;
      const int gs = (cgc >> 1) ^ (r >> 2);
      const bf16x8 val = *(const bf16x8*)&eb[r * 64 + gs * 16 + (cgc & 1) * 8];
      const long grow = m0 + wr * 64 + i * 16 + r;
      const int col = n0 + wc * 64 + cgc * 8;
      if (doq) {
        unsigned long long p8 = 0;
#pragma unroll
        for (int k = 0; k < 4; k++)
          p8 |= (unsigned long long)cvt2_fp8((float)val[2 * k],
                                             (float)val[2 * k + 1])
                << (16 * k);
        *(unsigned long long*)&qk8[grow * 2048 + col] = p8;
      } else {
        *(bf16x8*)&C[grow * 3072 + col] = val;
      }
    }
  }
}

// ---------------------------------------------------------------------------
// fp8 scores GEMM + exp epilogue (big path): 16 KB LDS, 4 K-iterations
// (high occupancy: round-11 64KB preload regressed). Bank-safe (row>>1)&3
// granule-XOR swizzle (round 10). XCD-chunked tile order (T1); rsP partial
// index uses the SWIZZLED n-block id (bijective over (nb, m-block)).
// fp8 conversion via HW cvt_pk (pairwise).
// ---------------------------------------------------------------------------
__global__ __launch_bounds__(256) void qk_exp_f8(
    const unsigned char* __restrict__ qk8, unsigned char* __restrict__ C,
    float scale, hb* __restrict__ rsP) {
  const int z = blockIdx.z;  // head
  const unsigned char* A = qk8 + z * 256;
  const unsigned char* B = qk8 + 1024 + z * 256;
  unsigned char* Cb = C + (long)z * SEQ * SEQ;
  __shared__ __align__(16) unsigned char smem8[16384];
  unsigned char* sA8 = smem8;
  unsigned char* sB8 = smem8 + 8192;
  XCD_SWZ128
  const int tid = threadIdx.x;
  const int wave = tid >> 6, lane = tid & 63;
  const int quad = lane >> 4, lm = lane & 15;
  const int wr = wave >> 1, wc = wave & 1;
  const int r8 = tid >> 2;
  const int cg8 = 16 * ((tid & 3) ^ ((r8 >> 1) & 3));  // bank-safe pre-swizzle
  const unsigned char* Ag = A + (long)(m0 + r8) * 2048 + cg8;
  const unsigned char* Bg = B + (long)(n0 + r8) * 2048 + cg8;

  f32x4 acc[4][4] = {};
  for (int kt = 0; kt < 256; kt += 64) {
    GLOAD_LDS16(Ag + kt, sA8 + wave * 1024);
    GLOAD_LDS16(Ag + kt + 64 * 2048, sA8 + 4096 + wave * 1024);
    GLOAD_LDS16(Bg + kt, sB8 + wave * 1024);
    GLOAD_LDS16(Bg + kt + 64 * 2048, sB8 + 4096 + wave * 1024);
    __syncthreads();
#pragma unroll
    for (int ks = 0; ks < 2; ks++) {
      long a8[4], b8[4];
#pragma unroll
      for (int i = 0; i < 4; i++) {
        const int row = wr * 64 + i * 16 + lm;
        a8[i] = *(const long*)&sA8[row * 64 +
                                   (((ks * 2 + (quad >> 1)) ^ ((row >> 1) & 3))
                                    << 4) +
                                   (quad & 1) * 8];
      }
#pragma unroll
      for (int i = 0; i < 4; i++) {
        const int row = wc * 64 + i * 16 + lm;
        b8[i] = *(const long*)&sB8[row * 64 +
                                   (((ks * 2 + (quad >> 1)) ^ ((row >> 1) & 3))
                                    << 4) +
                                   (quad & 1) * 8];
      }
#pragma unroll
      for (int i = 0; i < 4; i++)
#pragma unroll
        for (int j = 0; j < 4; j++)
          acc[i][j] = __builtin_amdgcn_mfma_f32_16x16x32_fp8_fp8(
              a8[i], b8[j], acc[i][j], 0, 0, 0);
    }
    __syncthreads();
  }

  unsigned char* eb8 = smem8 + wave * 1024;  // staging dead; wave-private
  float* rbuf = (float*)(smem8 + 8192);      // 256 floats
  float rs[4][4];
#pragma unroll
  for (int i = 0; i < 4; i++) {
    float r4[4] = {0.f, 0.f, 0.f, 0.f};
#pragma unroll
    for (int j = 0; j < 4; j++) {
      const int c = ((j ^ quad) << 4) + lm;  // swizzled col-block
      float e[4];
#pragma unroll
      for (int rr = 0; rr < 4; rr++) {
        e[rr] = __expf(acc[i][j][rr] * scale);
        r4[rr] += e[rr];
      }
      const unsigned u01 = cvt2_fp8_pos(e[0], e[1]);
      const unsigned u23 = cvt2_fp8_pos(e[2], e[3]);
      eb8[(quad * 4 + 0) * 64 + c] = (unsigned char)u01;
      eb8[(quad * 4 + 1) * 64 + c] = (unsigned char)(u01 >> 8);
      eb8[(quad * 4 + 2) * 64 + c] = (unsigned char)u23;
      eb8[(quad * 4 + 3) * 64 + c] = (unsigned char)(u23 >> 8);
    }
#pragma unroll
    for (int rr = 0; rr < 4; rr++) {
      r4[rr] += __shfl_xor(r4[rr], 1);
      r4[rr] += __shfl_xor(r4[rr], 2);
      r4[rr] += __shfl_xor(r4[rr], 4);
      r4[rr] += __shfl_xor(r4[rr], 8);
      rs[i][rr] = r4[rr];
    }
    {
      const int r = lane >> 2;
      const int cgc = lane & 3;
      const f32x4 val =
          *(const f32x4*)&eb8[r * 64 + ((cgc ^ (r >> 2)) << 4)];
      const long grow = m0 + wr * 64 + i * 16 + r;
      *(f32x4*)&Cb[grow * 4096 + n0 + wc * 64 + cgc * 16] = val;
    }
  }
  if (lm == 0) {
#pragma unroll
    for (int i = 0; i < 4; i++)
#pragma unroll
      for (int rr = 0; rr < 4; rr++)
        rbuf[(wr * 2 + wc) * 64 + i * 16 + quad * 4 + rr] = rs[i][rr];
  }
  __syncthreads();
  if (tid < 128) {
    const int lwr = tid >> 6, r64 = tid & 63;
    const float d = rbuf[lwr * 128 + r64] + rbuf[lwr * 128 + 64 + r64];
    rsP[((long)bx_ * NHEAD + z) * SEQ + m0 + lwr * 64 + r64] = f2b(d);
  }
}

// ---------------------------------------------------------------------------
// fp8 PV split-K (big path): pvpart[z=head*2+split] =
//   P8[head][:, split*2048:+2048] @ Vt8[head][:, same]^T  (bf16 partials)
// K-step 256 deep queue (16 gloads/barrier-window); bank-safe swizzle;
// XCD-chunked tile order.
// ---------------------------------------------------------------------------
__global__ __launch_bounds__(256) void pv_f8_splitk(
    const unsigned char* __restrict__ S, const unsigned char* __restrict__ Vt,
    hb* __restrict__ Cp) {
  const int z = blockIdx.z;  // head*2 + split
  const int head = z >> 1, split = z & 1;
  const unsigned char* A = S + (long)head * SEQ * SEQ + split * 2048;
  const unsigned char* B = Vt + ((long)head << 20) + split * 2048;
  hb* Cb = Cp + (long)z * SEQ * 256;
  __shared__ __align__(16) unsigned char smem8[65536];
  hb* smem = (hb*)smem8;  // alias for EPILOGUE_B16 (bytes [0,8192))
  unsigned char* sA8 = smem8;
  unsigned char* sB8 = smem8 + 32768;
  XCD_SWZ128
  const int tid = threadIdx.x;
  const int wave = tid >> 6, lane = tid & 63;
  const int quad = lane >> 4, lm = lane & 15;
  const int wr = wave >> 1, wc = wave & 1;
  const int r8 = tid >> 2;                       // 64 rows per gload
  const int cg8 = 16 * ((tid & 3) ^ ((r8 >> 1) & 3));  // bank-safe pre-swizzle
  const unsigned char* Ag = A + (long)(m0 + r8) * 4096 + cg8;
  const unsigned char* Bg = B + (long)(n0 + r8) * 4096 + cg8;

  f32x4 acc[4][4] = {};
  for (int kt = 0; kt < 2048; kt += 256) {
#pragma unroll
    for (int c = 0; c < 4; c++) {
      GLOAD_LDS16(Ag + kt + c * 64, sA8 + c * 8192 + wave * 1024);
      GLOAD_LDS16(Ag + kt + c * 64 + 64 * 4096,
                  sA8 + c * 8192 + 4096 + wave * 1024);
      GLOAD_LDS16(Bg + kt + c * 64, sB8 + c * 8192 + wave * 1024);
      GLOAD_LDS16(Bg + kt + c * 64 + 64 * 4096,
                  sB8 + c * 8192 + 4096 + wave * 1024);
    }
    __syncthreads();
#pragma unroll
    for (int c = 0; c < 4; c++) {
#pragma unroll
      for (int ks = 0; ks < 2; ks++) {
        long a8[4], b8[4];
#pragma unroll
        for (int i = 0; i < 4; i++) {
          const int row = wr * 64 + i * 16 + lm;
          a8[i] =
              *(const long*)&sA8[c * 8192 + row * 64 +
                                 (((ks * 2 + (quad >> 1)) ^ ((row >> 1) & 3))
                                  << 4) +
                                 (quad & 1) * 8];
        }
#pragma unroll
        for (int i = 0; i < 4; i++) {
          const int row = wc * 64 + i * 16 + lm;
          b8[i] =
              *(const long*)&sB8[c * 8192 + row * 64 +
                                 (((ks * 2 + (quad >> 1)) ^ ((row >> 1) & 3))
                                  << 4) +
                                 (quad & 1) * 8];
        }
#pragma unroll
        for (int i = 0; i < 4; i++)
#pragma unroll
          for (int j = 0; j < 4; j++)
            acc[i][j] = __builtin_amdgcn_mfma_f32_16x16x32_fp8_fp8(
                a8[i], b8[j], acc[i][j], 0, 0, 0);
      }
    }
    __syncthreads();
  }
  EPILOGUE_B16(Cb, 256)
}

// ---------------------------------------------------------------------------
// Split-K GEMM, fp32 partials: partial[z] = A[batch][:, s*Ksub:+Ksub] @ Bt^T
// ---------------------------------------------------------------------------
__global__ __launch_bounds__(256) void gemm_bt_splitk(
    const hb* __restrict__ A, long lda, long bA,
    const hb* __restrict__ B, long ldb, long bB,
    float* __restrict__ Cp, int ldcp, long pstride, int Ksub, int shift) {
  const int z = blockIdx.z;
  const int batch = z >> shift, split = z - (batch << shift);
  A += (long)batch * bA + (long)split * Ksub;
  B += (long)batch * bB + (long)split * Ksub;
  Cp += (long)z * pstride;
  __shared__ __align__(16) hb smem[2 * 128 * 64];
  hb* sA = smem;
  hb* sB = smem + 8192;
  GEMM_PROLOGUE
  const long lda_ = lda, ldb_ = ldb;
  const hb* Ag = A + (long)(m0 + r0) * lda + cg;
  const hb* Bg = B + (long)(n0 + r0) * ldb + cg;

  f32x4 acc[4][4] = {};
  GEMM_KLOOP64(Ksub)

  float* ef = (float*)smem + wave * 1024;  // 16x64 fp32 per wave
#pragma unroll
  for (int i = 0; i < 4; i++) {
#pragma unroll
    for (int j = 0; j < 4; j++) {
      const int c = ((j ^ quad) << 4) + lm;
#pragma unroll
      for (int rr = 0; rr < 4; rr++)
        ef[(quad * 4 + rr) * 64 + c] = acc[i][j][rr];
    }
#pragma unroll
    for (int p = 0; p < 4; p++) {
      const int r = p * 4 + (lane >> 4);
      const int cgc = lane & 15;
      const int gs = (cgc >> 2) ^ (r >> 2);
      const f32x4 val = *(const f32x4*)&ef[r * 64 + gs * 16 + (cgc & 3) * 4];
      const long grow = m0 + wr * 64 + i * 16 + r;
      *(f32x4*)&Cp[grow * ldcp + n0 + wc * 64 + cgc * 4] = val;
    }
  }
}

// ---------------------------------------------------------------------------
// Split-K GEMM, bf16 partials (each partial = full fp32 accumulation over
// Ksub, rounded once). Used by big-path ff2.
// ---------------------------------------------------------------------------
__global__ __launch_bounds__(256) void gemm_bt_splitk_b16(
    const hb* __restrict__ A, long lda, long bA,
    const hb* __restrict__ B, long ldb, long bB,
    hb* __restrict__ Cp, int ldcp, long pstride, int Ksub, int shift) {
  const int z = blockIdx.z;
  const int batch = z >> shift, split = z - (batch << shift);
  A += (long)batch * bA + (long)split * Ksub;
  B += (long)batch * bB + (long)split * Ksub;
  Cp += (long)z * pstride;
  __shared__ __align__(16) hb smem[2 * 128 * 64];
  hb* sA = smem;
  hb* sB = smem + 8192;
  GEMM_PROLOGUE
  const long lda_ = lda, ldb_ = ldb;
  const hb* Ag = A + (long)(m0 + r0) * lda + cg;
  const hb* Bg = B + (long)(n0 + r0) * ldb + cg;

  f32x4 acc[4][4] = {};
  GEMM_KLOOP64(Ksub)
  EPILOGUE_B16(Cp, ldcp)
}

// C[b][row,col] = f2b(sum_k part_fp32[(b<<shift)+k]); N = 1<<Nshift cols.
__global__ __launch_bounds__(256) void reduce_splitk(
    const float* __restrict__ part, long pstride, int nsplit, int shift,
    hb* __restrict__ C, long ldc, long bC, int Nshift) {
  const long idx = (long)blockIdx.x * 256 + threadIdx.x;
  const int batch = blockIdx.y;
  float v = 0.f;
  for (int k = 0; k < nsplit; k++)
    v += part[(long)((batch << shift) + k) * pstride + idx];
  const long row = idx >> Nshift;
  const long col = idx & ((1 << Nshift) - 1);
  C[(long)batch * bC + row * ldc + col] = f2b(v);
}

// ao[row, head*256+col] = (part0+part1) / sum_nb rsP[nb][head][row]
// 4 rows per block; vectorized I/O.
__global__ __launch_bounds__(256) void reduce_pv(
    const hb* __restrict__ part, const hb* __restrict__ rsP,
    hb* __restrict__ ao) {
  const int rb = blockIdx.x * 4, head = blockIdx.y, tid = threadIdx.x;
  __shared__ float dsh[4];
  if (tid < 128) {
    const int r = tid >> 5, nb = tid & 31;
    float p = b2f(rsP[((long)nb * NHEAD + head) * SEQ + rb + r]);
#pragma unroll
    for (int o = 16; o; o >>= 1) p += __shfl_down(p, o, 32);
    if (nb == 0) dsh[r] = p;
  }
  __syncthreads();
  const int r = tid >> 6, c4 = (tid & 63) * 4;
  const float den = dsh[r];
  const long base = ((long)(head * 2) * SEQ + rb + r) * 256 + c4;
  const bf16x4 p0 = *(const bf16x4*)&part[base];
  const bf16x4 p1 = *(const bf16x4*)&part[base + (long)SEQ * 256];
  bf16x4 o4;
#pragma unroll
  for (int k = 0; k < 4; k++)
    o4[k] = (__bf16)(((float)p0[k] + (float)p1[k]) / den);
  *(bf16x4*)&ao[(long)(rb + r) * 1024 + head * 256 + c4] = o4;
}

// ---------------------------------------------------------------------------
// MoE gather-GEMM: slotout[slot, :] = h[slot_token[slot], :] @ expertT[e]^T
// NOTE: eblk is indexed with the SWIZZLED y (by_), consistent with m0.
// ---------------------------------------------------------------------------
__global__ __launch_bounds__(256) void gemm_moe(
    const hb* __restrict__ h, const hb* __restrict__ expertT,
    const int* __restrict__ slot_token, const int* __restrict__ eblk,
    hb* __restrict__ slotout) {
  __shared__ __align__(16) hb smem[2 * 128 * 64];
  hb* sA = smem;
  hb* sB = smem + 8192;
  GEMM_PROLOGUE
  const int e = eblk[by_];
  if (e < 0) return;
  const int t0 = slot_token[m0 + r0];
  const int t1 = slot_token[m0 + r0 + 64];
  const hb* B = expertT + ((long)e << 20);
  const hb* Ag0 = h + (long)t0 * EMBED + cg;
  const hb* Ag1 = h + (long)t1 * EMBED + cg;
  const hb* Bg = B + (long)(n0 + r0) * EMBED + cg;

  f32x4 acc[4][4] = {};
  for (int kt = 0; kt < EMBED; kt += 64) {
    GLOAD_LDS16(Ag0 + kt, sA + wave * 512);
    GLOAD_LDS16(Ag0 + kt + 32, sA + 4096 + wave * 512);
    GLOAD_LDS16(Ag1 + kt, sA + 2048 + wave * 512);
    GLOAD_LDS16(Ag1 + kt + 32, sA + 6144 + wave * 512);
    GLOAD_LDS16(Bg + kt, sB + wave * 512);
    GLOAD_LDS16(Bg + kt + 32, sB + 4096 + wave * 512);
    GLOAD_LDS16(Bg + kt + 64 * EMBED, sB + 2048 + wave * 512);
    GLOAD_LDS16(Bg + kt + 64 * EMBED + 32, sB + 6144 + wave * 512);
    __syncthreads();
#pragma unroll
    for (int ks = 0; ks < 2; ks++) {
      bf16x8 av[4], bv[4];
#pragma unroll
      for (int i = 0; i < 4; i++) {
        const int row = wr * 64 + i * 16 + lm;
        av[i] = *(const bf16x8*)&sA[ks * 4096 + row * 32 + sw8];
      }
#pragma unroll
      for (int i = 0; i < 4; i++) {
        const int row = wc * 64 + i * 16 + lm;
        bv[i] = *(const bf16x8*)&sB[ks * 4096 + row * 32 + sw8];
      }
#pragma unroll
      for (int i = 0; i < 4; i++)
#pragma unroll
        for (int j = 0; j < 4; j++)
          acc[i][j] = __builtin_amdgcn_mfma_f32_16x16x32_bf16(av[i], bv[j],
                                                              acc[i][j], 0, 0, 0);
    }
    __syncthreads();
  }
  EPILOGUE_B16(slotout, EMBED)
}

// ---------------------------------------------------------------------------
// PRELUDE: weight transposes (blocks 0..9215) + fused h/gate (blocks 9216+)
// merged into ONE dispatch -- they are independent and previously ran
// serially (~23us + ~5us); co-scheduling overlaps the gate under the
// memory-bound transpose and removes one launch gap. Branch is block-uniform
// so barriers inside each arm are safe.
// Grid: 9216 + 4096 = 13312 blocks x 256 threads.
// ---------------------------------------------------------------------------
__global__ __launch_bounds__(256) void prelude_kernel(
    const float* __restrict__ expert_w, const float* __restrict__ in_proj_w,
    const float* __restrict__ out_proj_w, const float* __restrict__ ff1_w,
    const float* __restrict__ ff2_w, hb* __restrict__ expertT,
    hb* __restrict__ inprojT, hb* __restrict__ outprojT, hb* __restrict__ ff1T,
    hb* __restrict__ ff2T,
    const float* __restrict__ x, const int* __restrict__ timev,
    const float* __restrict__ state, const float* __restrict__ ttab,
    const float* __restrict__ gw, const float* __restrict__ gb,
    hb* __restrict__ h, int* __restrict__ tok_e, float* __restrict__ tok_w) {
  __shared__ hb tile[32][72];
  __shared__ float red[4][8];
  const int blk = blockIdx.x;
  if (blk >= 9216) {
    // ---- fused h = concat(x, t_emb, state) -> bf16, AND fp32 gate top-2.
    // Vectorized: c = tid*4 single pass; concat boundaries (496/512) are
    // float4-aligned for every thread.
    const int s = blk - 9216, tid = threadIdx.x;
    const int wv = tid >> 6, ln = tid & 63;
    const int t = timev[s];
    const int c = tid * 4;
    f32x4 v4;
    if (c < ADIM)
      v4 = *(const f32x4*)&x[(long)s * ADIM + c];
    else if (c < 512)
      v4 = *(const f32x4*)&ttab[t * 16 + (c - ADIM)];
    else
      v4 = *(const f32x4*)&state[(long)s * 512 + (c - 512)];
    bf16x4 h4;
#pragma unroll
    for (int k = 0; k < 4; k++) h4[k] = (__bf16)v4[k];
    *(bf16x4*)&h[(long)s * EMBED + c] = h4;
    float acc[8] = {0, 0, 0, 0, 0, 0, 0, 0};
#pragma unroll
    for (int k = 0; k < 4; k++) {
      const float* g = gw + (c + k) * 8;
#pragma unroll
      for (int n = 0; n < 8; n++) acc[n] += v4[k] * g[n];
    }
#pragma unroll
    for (int o = 32; o; o >>= 1)
#pragma unroll
      for (int n = 0; n < 8; n++) acc[n] += __shfl_down(acc[n], o);
    if (ln == 0)
#pragma unroll
      for (int n = 0; n < 8; n++) red[wv][n] = acc[n];
    __syncthreads();
    if (tid == 0) {
      float lg[8], m = -1e30f;
      for (int n = 0; n < 8; n++) {
        lg[n] = red[0][n] + red[1][n] + red[2][n] + red[3][n] + gb[n];
        m = fmaxf(m, lg[n]);
      }
      float den = 0.f;
      for (int n = 0; n < 8; n++) {
        lg[n] = expf(lg[n] - m);
        den += lg[n];
      }
      for (int n = 0; n < 8; n++) lg[n] /= den;
      int i1 = 0;
      for (int n = 1; n < 8; n++)
        if (lg[n] > lg[i1]) i1 = n;
      int i2 = (i1 == 0) ? 1 : 0;
      for (int n = 0; n < 8; n++) {
        if (n == i1) continue;
        if (lg[n] > lg[i2]) i2 = n;
      }
      tok_e[2 * s] = i1;
      tok_w[2 * s] = lg[i1];
      tok_e[2 * s + 1] = i2;
      tok_w[2 * s + 1] = lg[i2];
    }
    return;
  }
  // ---- weight transposes. 64(r)x32(c) input tiles, float4 global loads,
  // bf16x8 (16B/lane) global stores. LDS tile [c][r] with granule-XOR
  // swizzle keyed on (cidx>>3)&3 (two free 2-ways, m136).
  const int b = blk;
  const float* in;
  hb* outp;
  int Cin, ldin, ldout, bx, by;
  if (b < 4096) {  // expert_w: 8 x [1024,1024] -> [1024,1024]
    const int z = b >> 9, l = b & 511;
    bx = l & 31; by = l >> 5;
    in = expert_w + (long)z * 1048576; outp = expertT + (long)z * 1048576;
    Cin = 1024; ldin = 1024; ldout = 1024;
  } else if (b < 5632) {  // in_proj: [1024,3072] -> [3072,1024]
    const int l = b - 4096;
    bx = l % 96; by = l / 96;
    in = in_proj_w; outp = inprojT;
    Cin = 3072; ldin = 3072; ldout = 1024;
  } else if (b < 6144) {  // out_proj: [1024,1024]
    const int l = b - 5632;
    bx = l & 31; by = l >> 5;
    in = out_proj_w; outp = outprojT;
    Cin = 1024; ldin = 1024; ldout = 1024;
  } else if (b < 8192) {  // ff1: [1024,4096] -> [4096,1024]
    const int l = b - 6144;
    bx = l & 127; by = l >> 7;
    in = ff1_w; outp = ff1T;
    Cin = 4096; ldin = 4096; ldout = 1024;
  } else {  // ff2: [4096,496] -> [512,4096] zero-padded
    const int l = b - 8192;
    bx = l & 15; by = l >> 4;
    in = ff2_w; outp = ff2T;
    Cin = 496; ldin = 496; ldout = 4096;
  }
  const int c0 = bx * 32, r0 = by * 64;
  const int t = threadIdx.x;
  {
    const int rr = t >> 2, cb = (t & 3) * 8;
    const int c = c0 + cb;
    float v[8] = {0, 0, 0, 0, 0, 0, 0, 0};
    if (c < Cin) {
      const f32x4 p0 = *(const f32x4*)&in[(long)(r0 + rr) * ldin + c];
      const f32x4 p1 = *(const f32x4*)&in[(long)(r0 + rr) * ldin + c + 4];
#pragma unroll
      for (int k = 0; k < 4; k++) { v[k] = p0[k]; v[4 + k] = p1[k]; }
    }
#pragma unroll
    for (int j = 0; j < 8; j++) {
      const int cidx = cb + j;
      tile[cidx][rr ^ ((((cidx) >> 3) & 3) << 3)] = f2b(v[j]);
    }
  }
  __syncthreads();
  {
    const int oc = t >> 3, seg = t & 7;
    const bf16x8 val = *(const bf16x8*)&tile[oc][(seg ^ ((oc >> 3) & 3)) * 8];
    *(bf16x8*)&outp[(long)(c0 + oc) * ldout + r0 + seg * 8] = val;
  }
}

// bf16 transpose for V (per-head): out[c][r] = in[r][c]  (small path)
__global__ __launch_bounds__(256) void transpose_v(
    const hb* __restrict__ in, hb* __restrict__ out) {
  __shared__ hb tile[32][33];
  const int z = blockIdx.z;
  in += (long)z * 256;
  out += (long)z * 1048576;
  const int c0 = blockIdx.x * 32, r0 = blockIdx.y * 32;
  const int tx = threadIdx.x, ty = threadIdx.y;
#pragma unroll
  for (int i = 0; i < 32; i += 8)
    tile[ty + i][tx] = in[(long)(r0 + ty + i) * 3072 + c0 + tx];
  __syncthreads();
#pragma unroll
  for (int i = 0; i < 32; i += 8)
    out[(long)(c0 + ty + i) * 4096 + r0 + tx] = tile[tx][ty + i];
}

// fp8 transpose for V (big path): out8[c][r] = fp8(in[r][c]).
// HW cvt_pk when available (negatives + subnormals handled natively).
__global__ __launch_bounds__(256) void transpose_v8(
    const hb* __restrict__ in, unsigned char* __restrict__ out) {
  __shared__ hb tile[32][33];
  const int z = blockIdx.z;
  in += (long)z * 256;
  out += (long)z * 1048576;
  const int c0 = blockIdx.x * 32, r0 = blockIdx.y * 32;
  const int tx = threadIdx.x, ty = threadIdx.y;
#pragma unroll
  for (int i = 0; i < 32; i += 8)
    tile[ty + i][tx] = in[(long)(r0 + ty + i) * 3072 + c0 + tx];
  __syncthreads();
#pragma unroll
  for (int i = 0; i < 32; i += 8)
    out[(long)(c0 + ty + i) * 4096 + r0 + tx] =
        (unsigned char)cvt2_fp8(b2f(tile[tx][ty + i]), 0.f);
}

// ---------------------------------------------------------------------------
// Single-block grouping: histogram -> 128-aligned segments -> slot assignment.
// ---------------------------------------------------------------------------
__global__ __launch_bounds__(256) void group_kernel(
    const int* __restrict__ tok_e, int* __restrict__ slot_token,
    int* __restrict__ token_slot, int* __restrict__ eblk) {
  __shared__ int cnt[8], off[9], cur[8];
  const int tid = threadIdx.x;
  if (tid < 8) cnt[tid] = 0;
  for (int i = tid; i < NSLOT; i += 256) slot_token[i] = 0;  // padding -> tok 0
  __syncthreads();
  for (int i = tid; i < 2 * SEQ; i += 256) atomicAdd(&cnt[tok_e[i]], 1);
  __syncthreads();
  if (tid == 0) {
    int o = 0;
    for (int n = 0; n < 8; n++) {
      off[n] = o;
      cur[n] = o;
      o += (cnt[n] + 127) & ~127;
    }
    off[8] = o;
  }
  __syncthreads();
  if (tid < NSLOT / 128) {
    const int rb = tid * 128;
    int e = -1;
    for (int n = 0; n < 8; n++)
      if (rb >= off[n] && rb < off[n + 1]) e = n;
    eblk[tid] = e;
  }
  for (int i = tid; i < 2 * SEQ; i += 256) {
    const int e = tok_e[i];
    const int slot = atomicAdd(&cur[e], 1);
    slot_token[slot] = i >> 1;
    token_slot[i] = slot;
  }
}

// moe[s,:] = sum_k w_k * (slotout[slot_k,:] + expert_b[e_k,:])  (vectorized)
__global__ __launch_bounds__(256) void moe_combine_kernel(
    const hb* __restrict__ slotout, const int* __restrict__ token_slot,
    const float* __restrict__ tok_w, const int* __restrict__ tok_e,
    const float* __restrict__ eb, hb* __restrict__ moe) {
  const int s = blockIdx.x, tid = threadIdx.x;
  const int s0 = token_slot[2 * s], s1 = token_slot[2 * s + 1];
  const float w0 = tok_w[2 * s], w1 = tok_w[2 * s + 1];
  const int e0 = tok_e[2 * s], e1 = tok_e[2 * s + 1];
  const int c = tid * 4;
  const bf16x4 a0 = *(const bf16x4*)&slotout[(long)s0 * EMBED + c];
  const bf16x4 a1 = *(const bf16x4*)&slotout[(long)s1 * EMBED + c];
  const f32x4 b0 = *(const f32x4*)&eb[e0 * EMBED + c];
  const f32x4 b1 = *(const f32x4*)&eb[e1 * EMBED + c];
  bf16x4 o4;
#pragma unroll
  for (int k = 0; k < 4; k++)
    o4[k] = (__bf16)(w0 * ((float)a0[k] + b0[k]) + w1 * ((float)a1[k] + b1[k]));
  *(bf16x4*)&moe[(long)s * EMBED + c] = o4;
}

// ---------------------------------------------------------------------------
// Single-pass register-resident softmax: 4096 cols, 16 elems/thread in VGPRs.
// (small path only)
// ---------------------------------------------------------------------------
__global__ __launch_bounds__(256) void softmax_fast(hb* __restrict__ S,
                                                    float scale) {
  const long row = blockIdx.x;
  const int tid = threadIdx.x, wv = tid >> 6, ln = tid & 63;
  hb* p = S + row * 4096 + tid * 16;
  __shared__ float red[4];
  bf16x8 a0 = *(const bf16x8*)p;
  bf16x8 a1 = *(const bf16x8*)(p + 8);
  float v[16];
#pragma unroll
  for (int i = 0; i < 8; i++) {
    v[i] = (float)a0[i];
    v[8 + i] = (float)a1[i];
  }
  float m = v[0];
#pragma unroll
  for (int i = 1; i < 16; i++) m = fmaxf(m, v[i]);
#pragma unroll
  for (int o = 32; o; o >>= 1) m = fmaxf(m, __shfl_down(m, o));
  if (ln == 0) red[wv] = m;
  __syncthreads();
  const float M = fmaxf(fmaxf(red[0], red[1]), fmaxf(red[2], red[3])) * scale;
  __syncthreads();
  float sum = 0.f;
#pragma unroll
  for (int i = 0; i < 16; i++) {
    v[i] = __expf(v[i] * scale - M);
    sum += v[i];
  }
#pragma unroll
  for (int o = 32; o; o >>= 1) sum += __shfl_down(sum, o);
  if (ln == 0) red[wv] = sum;
  __syncthreads();
  const float inv = 1.f / (red[0] + red[1] + red[2] + red[3]);
#pragma unroll
  for (int i = 0; i < 8; i++) {
    a0[i] = (__bf16)(v[i] * inv);
    a1[i] = (__bf16)(v[8 + i] * inv);
  }
  *(bf16x8*)p = a0;
  *(bf16x8*)(p + 8) = a1;
}

// ---------------------------------------------------------------------------
// LayerNorm over ncol: t = in + resid?; out = (t-mean)*rsqrt(var)*g+b (bf16)
// Vectorized 4/thread (ncol multiple of 4; 1024 here).
// ---------------------------------------------------------------------------
__global__ __launch_bounds__(256) void ln_kernel(
    const hb* __restrict__ in, long ldin, const hb* __restrict__ resid,
    long ldr, const float* __restrict__ g, const float* __restrict__ beta,
    hb* __restrict__ outb, long ldout, int ncol) {
  const int s = blockIdx.x, tid = threadIdx.x, wv = tid >> 6, ln = tid & 63;
  __shared__ float buf[1024];
  __shared__ float red[4];
  float sum = 0.f, sq = 0.f;
  for (int c = tid * 4; c < ncol; c += 1024) {
    const bf16x4 iv = *(const bf16x4*)&in[(long)s * ldin + c];
#pragma unroll
    for (int k = 0; k < 4; k++) {
      float v = (float)iv[k];
      buf[c + k] = v;
    }
    if (resid) {
      const bf16x4 rv = *(const bf16x4*)&resid[(long)s * ldr + c];
#pragma unroll
      for (int k = 0; k < 4; k++) buf[c + k] += (float)rv[k];
    }
#pragma unroll
    for (int k = 0; k < 4; k++) {
      const float v = buf[c + k];
      sum += v;
      sq += v * v;
    }
  }
#pragma unroll
  for (int o = 32; o; o >>= 1) sum += __shfl_down(sum, o);
  if (ln == 0) red[wv] = sum;
  __syncthreads();
  const float S = red[0] + red[1] + red[2] + red[3];
  __syncthreads();
#pragma unroll
  for (int o = 32; o; o >>= 1) sq += __shfl_down(sq, o);
  if (ln == 0) red[wv] = sq;
  __syncthreads();
  const float Q = red[0] + red[1] + red[2] + red[3];
  const float mean = S / ncol;
  const float var = Q / ncol - mean * mean;
  const float r = rsqrtf(var + 1e-5f);
  for (int c = tid * 4; c < ncol; c += 1024) {
    const f32x4 gv = *(const f32x4*)&g[c];
    const f32x4 bv = *(const f32x4*)&beta[c];
    bf16x4 o4;
#pragma unroll
    for (int k = 0; k < 4; k++)
      o4[k] = (__bf16)((buf[c + k] - mean) * r * gv[k] + bv[k]);
    *(bf16x4*)&outb[(long)s * ldout + c] = o4;
  }
}

// ---------------------------------------------------------------------------
// Fused ff2 split-K reduce + bias + final LN over 496 cols -> fp32 d_out.
// fp32-partials variant (small path).
// ---------------------------------------------------------------------------
__global__ __launch_bounds__(256) void ln2_red_kernel(
    const float* __restrict__ part, long pstride,
    const float* __restrict__ bias, const float* __restrict__ g,
    const float* __restrict__ beta, float* __restrict__ out) {
  const int s = blockIdx.x, tid = threadIdx.x, wv = tid >> 6, ln = tid & 63;
  __shared__ float buf[512];
  __shared__ float red[4];
  float sum = 0.f, sq = 0.f;
  for (int c = tid; c < ADIM; c += 256) {
    const long idx = (long)s * 512 + c;
    float v = part[idx] + part[pstride + idx] + part[2 * pstride + idx] +
              part[3 * pstride + idx] + bias[c];
    buf[c] = v;
    sum += v;
    sq += v * v;
  }
#pragma unroll
  for (int o = 32; o; o >>= 1) sum += __shfl_down(sum, o);
  if (ln == 0) red[wv] = sum;
  __syncthreads();
  const float S = red[0] + red[1] + red[2] + red[3];
  __syncthreads();
#pragma unroll
  for (int o = 32; o; o >>= 1) sq += __shfl_down(sq, o);
  if (ln == 0) red[wv] = sq;
  __syncthreads();
  const float Q = red[0] + red[1] + red[2] + red[3];
  const float mean = S / ADIM;
  const float var = Q / ADIM - mean * mean;
  const float r = rsqrtf(var + 1e-5f);
  for (int c = tid; c < ADIM; c += 256)
    out[(long)s * ADIM + c] = (buf[c] - mean) * r * g[c] + beta[c];
}

// bf16-partials variant (big path): vectorized 4/thread (ADIM=496=124x4).
__global__ __launch_bounds__(256) void ln2_red_b16_kernel(
    const hb* __restrict__ part, long pstride,
    const float* __restrict__ bias, const float* __restrict__ g,
    const float* __restrict__ beta, float* __restrict__ out) {
  const int s = blockIdx.x, tid = threadIdx.x, wv = tid >> 6, ln = tid & 63;
  __shared__ float buf[512];
  __shared__ float red[4];
  float sum = 0.f, sq = 0.f;
  const int c = tid * 4;
  if (c < ADIM) {
    const long idx = (long)s * 512 + c;
    const bf16x4 p0 = *(const bf16x4*)&part[idx];
    const bf16x4 p1 = *(const bf16x4*)&part[pstride + idx];
    const bf16x4 p2 = *(const bf16x4*)&part[2 * pstride + idx];
    const bf16x4 p3 = *(const bf16x4*)&part[3 * pstride + idx];
    const f32x4 bv = *(const f32x4*)&bias[c];
#pragma unroll
    for (int k = 0; k < 4; k++) {
      const float v = (float)p0[k] + (float)p1[k] + (float)p2[k] +
                      (float)p3[k] + bv[k];
      buf[c + k] = v;
      sum += v;
      sq += v * v;
    }
  }
#pragma unroll
  for (int o = 32; o; o >>= 1) sum += __shfl_down(sum, o);
  if (ln == 0) red[wv] = sum;
  __syncthreads();
  const float S = red[0] + red[1] + red[2] + red[3];
  __syncthreads();
#pragma unroll
  for (int o = 32; o; o >>= 1) sq += __shfl_down(sq, o);
  if (ln == 0) red[wv] = sq;
  __syncthreads();
  const float Q = red[0] + red[1] + red[2] + red[3];
  const float mean = S / ADIM;
  const float var = Q / ADIM - mean * mean;
  const float r = rsqrtf(var + 1e-5f);
  if (c < ADIM) {
    const f32x4 gv = *(const f32x4*)&g[c];
    const f32x4 bt = *(const f32x4*)&beta[c];
    f32x4 o4;
#pragma unroll
    for (int k = 0; k < 4; k++)
      o4[k] = (buf[c + k] - mean) * r * gv[k] + bt[k];
    *(f32x4*)&out[(long)s * ADIM + c] = o4;
  }
}

// ---------------------------------------------------------------------------
extern "C" void kernel_launch(void* const* d_in, const int* in_sizes, int n_in,
                              void* d_out, int out_size, void* d_ws,
                              size_t ws_size, hipStream_t stream) {
  const float* x = (const float*)d_in[0];
  const int* timev = (const int*)d_in[1];
  const float* state = (const float*)d_in[2];
  const float* ttab = (const float*)d_in[3];
  const float* expert_w = (const float*)d_in[4];
  const float* expert_b = (const float*)d_in[5];
  const float* gate_w = (const float*)d_in[6];
  const float* gate_b = (const float*)d_in[7];
  const float* in_proj_w = (const float*)d_in[8];
  const float* in_proj_b = (const float*)d_in[9];
  const float* out_proj_w = (const float*)d_in[10];
  const float* out_proj_b = (const float*)d_in[11];
  const float* ln1_g = (const float*)d_in[12];
  const float* ln1_b = (const float*)d_in[13];
  const float* ff1_w = (const float*)d_in[14];
  const float* ff1_b = (const float*)d_in[15];
  const float* ff2_w = (const float*)d_in[16];
  const float* ff2_b = (const float*)d_in[17];
  const float* ln2_g = (const float*)d_in[18];
  const float* ln2_b = (const float*)d_in[19];
  float* out = (float*)d_out;

  char* w = (char*)d_ws;
  const long MB = 1048576;
  // big path (single-pass 4-head attention, fp8 scores): peak < 191 MB.
  // ws_size is constant per harness instance -> branch is graph-safe.
  const bool big = ws_size >= (size_t)(192 * MB);

  // ---- big-path lifetimes (audited):
  //  0-24  qkv        (V region written step4; dead after transpose_v8)
  //  0-16  pvpart     (bf16 PV partials; written AFTER scores GEMM -> safe)
  // 24-88  scores8    (fp8; live scores GEMM .. PV)
  // 24-32  ao2 / 32-40 out1 / 40-72 ffmid / 72-88 partb16(ff2) (post-attn,
  //        scores8 dead by then)
  // 88-96  qk8        (fp8 Q,K; written by gemm_bt_qkv, read by qk_exp_f8)
  // 152-160 moe (live until ln1) | 160-161 vt8 | 168-182 weights | 182-190 ao
  // meta at 190: tok/slot arrays (<136KB) + rsP at +160KB (1MB bf16
  //   [32 nb][4 head][4096 row] exp partial row-sums; plain stores)
  hb* expertT = (hb*)(w + 0 * MB);          // 16 MB, dead after gemm_moe
  hb* slotout = (hb*)(w + 16 * MB);         // 18.9 MB, dead after combine
  hb* h = (hb*)(w + 35 * MB);               //  8 MB, dead after gemm_moe
  hb* inprojT = (hb*)(w + 43 * MB);         //  6 MB, dead after qkv GEMM
  hb* outprojT = (hb*)(w + (big ? 168 : 49) * MB);
  hb* ff1T = (hb*)(w + (big ? 170 : 51) * MB);
  hb* ff2T = (hb*)(w + (big ? 178 : 59) * MB);
  const long metaOff = (big ? 190 : 63) * MB;
  int* tok_e = (int*)(w + metaOff);
  float* tok_w = (float*)(w + metaOff + 32768);
  int* slot_token = (int*)(w + metaOff + 65536);
  int* token_slot = (int*)(w + metaOff + 102400);
  int* eblk = (int*)(w + metaOff + 135168);
  hb* rsP = (hb*)(w + metaOff + 163840);    // 1 MB exp row-sum partials
  hb* moe = (hb*)(w + (big ? 152 : 64) * MB);   // live until ln1
  hb* qkv = (hb*)(w + (big ? 0 : 72) * MB);
  unsigned char* scores8 = (unsigned char*)(w + 24 * MB);  // big: 64 MB fp8
  hb* scores = (hb*)(w + 96 * MB);              // small path bf16 scores
  unsigned char* qk8 = (unsigned char*)(w + 88 * MB);      // big: 8 MB fp8 Q,K
  unsigned char* vt8 = (unsigned char*)(w + 160 * MB);     // big: 4 MB fp8
  hb* vt = (hb*)(w + 8 * MB);                   // small path bf16 V^T
  hb* ao = (hb*)(w + (big ? 182 : 0) * MB);
  hb* ao2 = (hb*)(w + (big ? 24 : 8) * MB);
  hb* out1 = (hb*)(w + (big ? 32 : 132) * MB);
  hb* ffmid = (hb*)(w + (big ? 40 : 96) * MB);
  float* part = (float*)(w + (big ? 72 : 16) * MB);  // fp32 split-K partials
  hb* partb16 = (hb*)(w + (big ? 72 : 16) * MB);     // big: bf16 ff2 partials
  hb* pvpart = (hb*)(w + 0 * MB);  // big: 16 MB bf16 PV partials (qkv dead)
  (void)in_sizes; (void)n_in; (void)out_size;

  // 1+2) prelude: weight transposes + fused h/gate in ONE dispatch, then
  //      grouping
  prelude_kernel<<<dim3(9216 + SEQ), dim3(256), 0, stream>>>(
      expert_w, in_proj_w, out_proj_w, ff1_w, ff2_w, expertT, inprojT,
      outprojT, ff1T, ff2T, x, timev, state, ttab, gate_w, gate_b, h, tok_e,
      tok_w);
  group_kernel<<<dim3(1), 256, 0, stream>>>(tok_e, slot_token, token_slot, eblk);

  // 3) grouped MoE: gather-GEMM + combine
  gemm_moe<<<dim3(8, NSLOT / 128), 256, 0, stream>>>(h, expertT, slot_token,
                                                     eblk, slotout);
  moe_combine_kernel<<<dim3(SEQ), 256, 0, stream>>>(slotout, token_slot, tok_w,
                                                    tok_e, expert_b, moe);

  // 4) qkv = moe @ in_proj + b (big: fp8 Q,K to qk8, bf16 V to qkv);
  //    then V^T for all 4 heads
  if (big) {
    gemm_bt_qkv<<<dim3(24, 32), 256, 0, stream>>>(moe, inprojT, qkv,
                                                  in_proj_b, qk8);
    transpose_v8<<<dim3(8, 128, 4), dim3(32, 8), 0, stream>>>(qkv + 2048, vt8);
  } else {
    gemm_bt<<<dim3(24, 32, 1), 256, 0, stream>>>(moe, 1024, 0, inprojT, 1024,
                                                 0, qkv, 3072, 0, 1024,
                                                 in_proj_b, 0);
    transpose_v<<<dim3(8, 128, 4), dim3(32, 8), 0, stream>>>(qkv + 2048, vt);
  }

  // 5) attention
  if (big) {
    // all 4 heads: fp8 QK^T GEMM (16KB-LDS, XCD-swizzled) with fused
    // exp -> fp8 scores + bf16 partial row-sums, then fp8 PV (split-K=2,
    // K-step 256 deep-queue), then normalize-reduce.
    qk_exp_f8<<<dim3(32, 32, 4), 256, 0, stream>>>(qk8, scores8, 0.0625f, rsP);
    pv_f8_splitk<<<dim3(2, 32, 8), 256, 0, stream>>>(scores8, vt8, pvpart);
    reduce_pv<<<dim3(1024, 4), 256, 0, stream>>>(pvpart, rsP, ao);
  } else {
    for (int hp = 0; hp < 2; ++hp) {
      const hb* qb = qkv + hp * 512;
      const hb* kb = qkv + 1024 + hp * 512;
      gemm_bt<<<dim3(32, 32, 2), 256, 0, stream>>>(
          qb, 3072, 256, kb, 3072, 256, scores, 4096, (long)SEQ * SEQ, HDIM,
          nullptr, 0);
      softmax_fast<<<dim3(2 * SEQ), 256, 0, stream>>>(scores, 0.0625f);
      gemm_bt_splitk<<<dim3(2, 32, 8), 256, 0, stream>>>(
          scores, 4096, (long)SEQ * SEQ, vt + (long)hp * 2097152, 4096,
          1048576L, part, 256, (long)SEQ * 256, 1024, 2);
      reduce_splitk<<<dim3(4096, 2), 256, 0, stream>>>(
          part, (long)SEQ * 256, 4, 2, ao + hp * 512, 1024, 256, 8);
    }
  }

  // 6) out_proj, residual LN
  gemm_bt<<<dim3(8, 32, 1), 256, 0, stream>>>(ao, 1024, 0, outprojT, 1024, 0,
                                              ao2, 1024, 0, 1024, out_proj_b, 0);
  ln_kernel<<<dim3(SEQ), 256, 0, stream>>>(moe, 1024, ao2, 1024, ln1_g, ln1_b,
                                           out1, 1024, 1024);

  // 7) FFN; ff2 via split-K=4 (bf16 partials on big path), reduce fused
  //    into the final LN.
  gemm_bt<<<dim3(32, 32, 1), 256, 0, stream>>>(out1, 1024, 0, ff1T, 1024, 0,
                                               ffmid, 4096, 0, 1024, ff1_b, 1);
  if (big) {
    gemm_bt_splitk_b16<<<dim3(4, 32, 4), 256, 0, stream>>>(
        ffmid, 4096, 0, ff2T, 4096, 0, partb16, 512, (long)SEQ * 512, 1024, 2);
    ln2_red_b16_kernel<<<dim3(SEQ), 256, 0, stream>>>(
        partb16, (long)SEQ * 512, ff2_b, ln2_g, ln2_b, out);
  } else {
    gemm_bt_splitk<<<dim3(4, 32, 4), 256, 0, stream>>>(
        ffmid, 4096, 0, ff2T, 4096, 0, part, 512, (long)SEQ * 512, 1024, 2);
    ln2_red_kernel<<<dim3(SEQ), 256, 0, stream>>>(part, (long)SEQ * 512, ff2_b,
                                                  ln2_g, ln2_b, out);
  }
}